// Round 4
// baseline (1702.882 us; speedup 1.0000x reference)
//
#include <hip/hip_runtime.h>
#include <hip/hip_bf16.h>

static constexpr int N_ = 50000;
static constexpr int E_ = 800000;
static constexpr int CAP = 128;   // per-wave LDS edge cache (max degree fast-path)

// ---------------- CSR build ----------------
__global__ void k_hist(const int* __restrict__ ei, int* __restrict__ deg) {
  int e = blockIdx.x * blockDim.x + threadIdx.x;
  if (e < E_) atomicAdd(&deg[ei[E_ + e]], 1);
}

__global__ __launch_bounds__(1024) void k_scan_blk(const int* __restrict__ deg,
                                                   int* __restrict__ off,
                                                   int* __restrict__ bsum) {
  __shared__ int sm[1024];
  int t = threadIdx.x;
  int i = blockIdx.x * 1024 + t;
  int v = (i < N_) ? deg[i] : 0;
  sm[t] = v;
  __syncthreads();
  for (int s = 1; s < 1024; s <<= 1) {
    int u = (t >= s) ? sm[t - s] : 0;
    __syncthreads();
    sm[t] += u;
    __syncthreads();
  }
  if (i < N_) off[i] = sm[t] - v;
  if (t == 1023) bsum[blockIdx.x] = sm[t];
}

__global__ void k_scan_top(int* __restrict__ bsum, int nb) {
  int t = threadIdx.x;  // 64
  int v = (t < nb) ? bsum[t] : 0;
  int orig = v;
  for (int s = 1; s < 64; s <<= 1) {
    int u = __shfl_up(v, s);
    if (t >= s) v += u;
  }
  if (t < nb) bsum[t] = v - orig;
}

__global__ void k_scan_add(int* __restrict__ off, const int* __restrict__ bsum,
                           int* __restrict__ cur) {
  int i = blockIdx.x * blockDim.x + threadIdx.x;
  if (i < N_) {
    int o = off[i] + bsum[i >> 10];
    off[i] = o;
    cur[i] = o;
  }
  if (i == 0) off[N_] = E_;
}

__global__ void k_scatter(const int* __restrict__ ei, int* __restrict__ cursor,
                          int2* __restrict__ csr_es) {
  int e = blockIdx.x * blockDim.x + threadIdx.x;
  if (e < E_) {
    int s = ei[e];
    int d = ei[E_ + e];
    int p = atomicAdd(&cursor[d], 1);
    csr_es[p] = make_int2(e, s);
  }
}

// ---------------- Encoder: node-per-lane, fused 2 layers ----------------
__global__ __launch_bounds__(256, 1) void k_enc(
    const float* __restrict__ x, const int* __restrict__ ntype, const int* __restrict__ sid,
    const float* __restrict__ temb, const float* __restrict__ semb,
    const float* __restrict__ w1, const float* __restrict__ b1,
    const float* __restrict__ w2, const float* __restrict__ b2,
    float* __restrict__ hout) {
  int v = blockIdx.x * 256 + threadIdx.x;
  if (v >= N_) v = N_ - 1;   // clamp: duplicate identical work, branch-free
  float in[23];
#pragma unroll
  for (int i = 0; i < 7; ++i) in[i] = x[v * 7 + i];
  int nt = ntype[v], sd = sid[v];
#pragma unroll
  for (int i = 0; i < 8; ++i) in[7 + i] = temb[nt * 8 + i];
#pragma unroll
  for (int i = 0; i < 8; ++i) in[15 + i] = semb[sd * 8 + i];
  float h1[64];
#pragma unroll
  for (int j = 0; j < 64; ++j) {
    float a = b1[j];
#pragma unroll
    for (int i = 0; i < 23; ++i) a = fmaf(in[i], w1[i * 64 + j], a);
    h1[j] = fmaxf(a, 0.f);
  }
  for (int j0 = 0; j0 < 64; j0 += 8) {   // rolled: weights via scalar loads
    float acc[8];
#pragma unroll
    for (int u = 0; u < 8; ++u) acc[u] = b2[j0 + u];
#pragma unroll
    for (int i = 0; i < 64; ++i) {
      float hv = h1[i];
#pragma unroll
      for (int u = 0; u < 8; ++u) acc[u] = fmaf(hv, w2[i * 64 + j0 + u], acc[u]);
    }
    *(float4*)(hout + (size_t)v * 64 + j0)     = make_float4(acc[0], acc[1], acc[2], acc[3]);
    *(float4*)(hout + (size_t)v * 64 + j0 + 4) = make_float4(acc[4], acc[5], acc[6], acc[7]);
  }
}

// ---------------- GAT node transforms: node-per-lane ----------------
__global__ __launch_bounds__(256, 1) void k_xlxr(
    const float* __restrict__ h,
    const float* __restrict__ wl, const float* __restrict__ bl,
    const float* __restrict__ wr, const float* __restrict__ br,
    float* __restrict__ xl, float* __restrict__ xr) {
  int v = blockIdx.x * 256 + threadIdx.x;
  if (v >= N_) v = N_ - 1;
  float hreg[64];
#pragma unroll
  for (int i = 0; i < 16; ++i) {
    float4 t = *(const float4*)(h + (size_t)v * 64 + i * 4);
    hreg[i * 4] = t.x; hreg[i * 4 + 1] = t.y; hreg[i * 4 + 2] = t.z; hreg[i * 4 + 3] = t.w;
  }
  for (int j0 = 0; j0 < 64; j0 += 8) {
    float al[8], ar[8];
#pragma unroll
    for (int u = 0; u < 8; ++u) { al[u] = bl[j0 + u]; ar[u] = br[j0 + u]; }
#pragma unroll
    for (int i = 0; i < 64; ++i) {
      float hv = hreg[i];
#pragma unroll
      for (int u = 0; u < 8; ++u) {
        al[u] = fmaf(hv, wl[i * 64 + j0 + u], al[u]);
        ar[u] = fmaf(hv, wr[i * 64 + j0 + u], ar[u]);
      }
    }
    *(float4*)(xl + (size_t)v * 64 + j0)     = make_float4(al[0], al[1], al[2], al[3]);
    *(float4*)(xl + (size_t)v * 64 + j0 + 4) = make_float4(al[4], al[5], al[6], al[7]);
    *(float4*)(xr + (size_t)v * 64 + j0)     = make_float4(ar[0], ar[1], ar[2], ar[3]);
    *(float4*)(xr + (size_t)v * 64 + j0 + 4) = make_float4(ar[4], ar[5], ar[6], ar[7]);
  }
}

// ---------------- Fused GAT: 4 edges x 16 lanes per wave ----------------
template <bool RELU>
__global__ __launch_bounds__(256) void k_fused(
    const int* __restrict__ off, const int2* __restrict__ csr_es,
    const float* __restrict__ eattr,
    const float* __restrict__ xl, const float* __restrict__ xr,
    const float* __restrict__ we, const float* __restrict__ att,
    const float* __restrict__ bias,
    float* __restrict__ hout, float* __restrict__ alpha) {
  __shared__ float exbuf[4][CAP * 4];
  __shared__ int ebuf[4][CAP];
  int tid = threadIdx.x;
  int lane = tid & 63, wv = tid >> 6;
  int slot = lane >> 4;       // edge slot 0..3
  int q = lane & 15;          // channel quad: channels q*4 .. q*4+3
  int head = q >> 2;          // head of my channels
  int sb = slot << 4;         // slot base lane
  // per-lane weight registers
  float wef[6][4], att4[4], b4[4];
#pragma unroll
  for (int i = 0; i < 6; ++i)
#pragma unroll
    for (int r = 0; r < 4; ++r) wef[i][r] = we[i * 64 + q * 4 + r];
#pragma unroll
  for (int r = 0; r < 4; ++r) { att4[r] = att[q * 4 + r]; b4[r] = bias[q * 4 + r]; }

  int wid = (blockIdx.x * blockDim.x + tid) >> 6;
  int nw = (gridDim.x * blockDim.x) >> 6;
  for (int v = wid; v < N_; v += nw) {
    int p0 = off[v], p1 = off[v + 1];
    int cnt = p1 - p0;
    float4 xr4 = *(const float4*)(xr + (size_t)v * 64 + q * 4);
    float num0 = 0.f, num1 = 0.f, num2 = 0.f, num3 = 0.f, den = 0.f;
    int p = p0 + slot;
    int2 es = (p < p1) ? csr_es[p] : make_int2(0, 0);
    for (int base = 0; base < cnt; base += 4) {
      bool valid = (p0 + base + slot) < p1;
      int e = es.x, s = es.y;
      int pn = p0 + base + 4 + slot;
      int2 esn = (pn < p1) ? csr_es[pn] : make_int2(0, 0);
      float ea = (valid && q < 6) ? eattr[(size_t)e * 6 + q] : 0.f;
      float4 xls = valid ? *(const float4*)(xl + (size_t)s * 64 + q * 4)
                         : make_float4(0.f, 0.f, 0.f, 0.f);
      float m0 = xls.x + xr4.x, m1 = xls.y + xr4.y, m2 = xls.z + xr4.z, m3 = xls.w + xr4.w;
#pragma unroll
      for (int i = 0; i < 6; ++i) {
        float eai = __shfl(ea, sb + i);
        m0 = fmaf(eai, wef[i][0], m0);
        m1 = fmaf(eai, wef[i][1], m1);
        m2 = fmaf(eai, wef[i][2], m2);
        m3 = fmaf(eai, wef[i][3], m3);
      }
      m0 = (m0 > 0.f) ? m0 : 0.2f * m0;
      m1 = (m1 > 0.f) ? m1 : 0.2f * m1;
      m2 = (m2 > 0.f) ? m2 : 0.2f * m2;
      m3 = (m3 > 0.f) ? m3 : 0.2f * m3;
      float t = m0 * att4[0];
      t = fmaf(m1, att4[1], t);
      t = fmaf(m2, att4[2], t);
      t = fmaf(m3, att4[3], t);
      t += __shfl_xor(t, 1);
      t += __shfl_xor(t, 2);
      float ex = valid ? __expf(t) : 0.f;
      den += ex;
      num0 = fmaf(xls.x, ex, num0);
      num1 = fmaf(xls.y, ex, num1);
      num2 = fmaf(xls.z, ex, num2);
      num3 = fmaf(xls.w, ex, num3);
      int idx = base + slot;
      if (valid && idx < CAP) {
        if ((lane & 3) == 0) exbuf[wv][idx * 4 + head] = ex;
        if (q == 0) ebuf[wv][idx] = e;
      }
      es = esn;
    }
    // combine 4 slots
    num0 += __shfl_xor(num0, 16); num0 += __shfl_xor(num0, 32);
    num1 += __shfl_xor(num1, 16); num1 += __shfl_xor(num1, 32);
    num2 += __shfl_xor(num2, 16); num2 += __shfl_xor(num2, 32);
    num3 += __shfl_xor(num3, 16); num3 += __shfl_xor(num3, 32);
    den  += __shfl_xor(den, 16);  den  += __shfl_xor(den, 32);
    float dinv = 1.f / (den + 1e-16f);
    float o0 = fmaf(num0, dinv, b4[0]);
    float o1 = fmaf(num1, dinv, b4[1]);
    float o2 = fmaf(num2, dinv, b4[2]);
    float o3 = fmaf(num3, dinv, b4[3]);
    if (RELU) {
      o0 = fmaxf(o0, 0.f); o1 = fmaxf(o1, 0.f); o2 = fmaxf(o2, 0.f); o3 = fmaxf(o3, 0.f);
    }
    if (slot == 0)
      *(float4*)(hout + (size_t)v * 64 + q * 4) = make_float4(o0, o1, o2, o3);
    // alpha epilogue
    float dh = __shfl(dinv, (lane & 3) << 2);  // dinv of head (lane&3)
    if (cnt <= CAP) {
      for (int base2 = 0; base2 < cnt; base2 += 16) {
        int idx = base2 + (lane >> 2);
        if (idx < cnt) {
          float exv = exbuf[wv][idx * 4 + (lane & 3)];
          int e = ebuf[wv][idx];
          alpha[(size_t)e * 4 + (lane & 3)] = exv * dh;
        }
      }
    } else {
      // recompute fallback (degree > CAP): whole wave per edge
      for (int pp = p0; pp < p1; ++pp) {
        int2 es2 = csr_es[pp];
        int e = es2.x, s = es2.y;
        float ea = (q < 6) ? eattr[(size_t)e * 6 + q] : 0.f;
        float4 xls = *(const float4*)(xl + (size_t)s * 64 + q * 4);
        float m0 = xls.x + xr4.x, m1 = xls.y + xr4.y, m2 = xls.z + xr4.z, m3 = xls.w + xr4.w;
#pragma unroll
        for (int i = 0; i < 6; ++i) {
          float eai = __shfl(ea, i);  // all slots same edge; take slot-0 lanes' ea
          m0 = fmaf(eai, wef[i][0], m0);
          m1 = fmaf(eai, wef[i][1], m1);
          m2 = fmaf(eai, wef[i][2], m2);
          m3 = fmaf(eai, wef[i][3], m3);
        }
        m0 = (m0 > 0.f) ? m0 : 0.2f * m0;
        m1 = (m1 > 0.f) ? m1 : 0.2f * m1;
        m2 = (m2 > 0.f) ? m2 : 0.2f * m2;
        m3 = (m3 > 0.f) ? m3 : 0.2f * m3;
        float t = m0 * att4[0];
        t = fmaf(m1, att4[1], t);
        t = fmaf(m2, att4[2], t);
        t = fmaf(m3, att4[3], t);
        t += __shfl_xor(t, 1);
        t += __shfl_xor(t, 2);
        if (slot == 0 && (lane & 3) == 0)
          alpha[(size_t)e * 4 + head] = __expf(t) * dinv;
      }
    }
  }
}

// ---------------- GRU: node-per-lane, fully fused ----------------
__global__ __launch_bounds__(256, 1) void k_gru(
    const float* __restrict__ h, const float* __restrict__ hs,
    const float* __restrict__ wih, const float* __restrict__ bih,
    const float* __restrict__ whh, const float* __restrict__ bhh,
    float* __restrict__ nhout) {
  int v = blockIdx.x * 256 + threadIdx.x;
  if (v >= N_) v = N_ - 1;
  float hr_[64], sr_[64];
#pragma unroll
  for (int i = 0; i < 16; ++i) {
    float4 a = *(const float4*)(h + (size_t)v * 64 + i * 4);
    hr_[i * 4] = a.x; hr_[i * 4 + 1] = a.y; hr_[i * 4 + 2] = a.z; hr_[i * 4 + 3] = a.w;
    float4 b = *(const float4*)(hs + (size_t)v * 64 + i * 4);
    sr_[i * 4] = b.x; sr_[i * 4 + 1] = b.y; sr_[i * 4 + 2] = b.z; sr_[i * 4 + 3] = b.w;
  }
  for (int j0 = 0; j0 < 64; j0 += 4) {   // rolled; weights via scalar loads
    float air[4], aiz[4], ain[4], ahr[4], ahz[4], ahn[4];
#pragma unroll
    for (int u = 0; u < 4; ++u) {
      air[u] = bih[j0 + u]; aiz[u] = bih[64 + j0 + u]; ain[u] = bih[128 + j0 + u];
      ahr[u] = bhh[j0 + u]; ahz[u] = bhh[64 + j0 + u]; ahn[u] = bhh[128 + j0 + u];
    }
#pragma unroll
    for (int i = 0; i < 64; ++i) {
      float hv = hr_[i], sv = sr_[i];
#pragma unroll
      for (int u = 0; u < 4; ++u) {
        air[u] = fmaf(hv, wih[i * 192 + j0 + u], air[u]);
        aiz[u] = fmaf(hv, wih[i * 192 + 64 + j0 + u], aiz[u]);
        ain[u] = fmaf(hv, wih[i * 192 + 128 + j0 + u], ain[u]);
        ahr[u] = fmaf(sv, whh[i * 192 + j0 + u], ahr[u]);
        ahz[u] = fmaf(sv, whh[i * 192 + 64 + j0 + u], ahz[u]);
        ahn[u] = fmaf(sv, whh[i * 192 + 128 + j0 + u], ahn[u]);
      }
    }
    float o[4];
#pragma unroll
    for (int u = 0; u < 4; ++u) {
      float r = 1.f / (1.f + __expf(-(air[u] + ahr[u])));
      float z = 1.f / (1.f + __expf(-(aiz[u] + ahz[u])));
      float n = tanhf(ain[u] + r * ahn[u]);
      float sv = hs[(size_t)v * 64 + j0 + u];
      o[u] = (1.f - z) * n + z * sv;
    }
    *(float4*)(nhout + (size_t)v * 64 + j0) = make_float4(o[0], o[1], o[2], o[3]);
  }
}

// ---------------- Decoder: node-per-lane, fused 2 layers ----------------
__global__ __launch_bounds__(256, 1) void k_dec(
    const float* __restrict__ nh,
    const float* __restrict__ w1, const float* __restrict__ b1,
    const float* __restrict__ w2, const float* __restrict__ b2,
    float* __restrict__ out) {
  int v = blockIdx.x * 256 + threadIdx.x;
  if (v >= N_) v = N_ - 1;
  float hreg[64];
#pragma unroll
  for (int i = 0; i < 16; ++i) {
    float4 t = *(const float4*)(nh + (size_t)v * 64 + i * 4);
    hreg[i * 4] = t.x; hreg[i * 4 + 1] = t.y; hreg[i * 4 + 2] = t.z; hreg[i * 4 + 3] = t.w;
  }
  float d[64];
#pragma unroll
  for (int j = 0; j < 64; ++j) {
    float a = b1[j];
#pragma unroll
    for (int i = 0; i < 64; ++i) a = fmaf(hreg[i], w1[i * 64 + j], a);
    d[j] = fmaxf(a, 0.f);
  }
  float o[7];
#pragma unroll
  for (int u = 0; u < 7; ++u) o[u] = b2[u];
#pragma unroll
  for (int i = 0; i < 64; ++i) {
    float dv = d[i];
#pragma unroll
    for (int u = 0; u < 7; ++u) o[u] = fmaf(dv, w2[i * 7 + u], o[u]);
  }
#pragma unroll
  for (int u = 0; u < 7; ++u) out[(size_t)v * 7 + u] = o[u];
}

extern "C" void kernel_launch(void* const* d_in, const int* in_sizes, int n_in,
                              void* d_out, int out_size, void* d_ws, size_t ws_size,
                              hipStream_t stream) {
  const float* x      = (const float*)d_in[0];
  const int* ntype    = (const int*)d_in[1];
  const int* sid      = (const int*)d_in[2];
  const int* ei       = (const int*)d_in[3];
  const float* eattr  = (const float*)d_in[4];
  const float* hs     = (const float*)d_in[5];
  const float* temb   = (const float*)d_in[6];
  const float* semb   = (const float*)d_in[7];
  const float* enc_w1 = (const float*)d_in[8];
  const float* enc_b1 = (const float*)d_in[9];
  const float* enc_w2 = (const float*)d_in[10];
  const float* enc_b2 = (const float*)d_in[11];
  const float* g1_wl  = (const float*)d_in[12];
  const float* g1_bl  = (const float*)d_in[13];
  const float* g1_wr  = (const float*)d_in[14];
  const float* g1_br  = (const float*)d_in[15];
  const float* g1_we  = (const float*)d_in[16];
  const float* g1_att = (const float*)d_in[17];
  const float* g1_bias= (const float*)d_in[18];
  const float* g2_wl  = (const float*)d_in[19];
  const float* g2_bl  = (const float*)d_in[20];
  const float* g2_wr  = (const float*)d_in[21];
  const float* g2_br  = (const float*)d_in[22];
  const float* g2_we  = (const float*)d_in[23];
  const float* g2_att = (const float*)d_in[24];
  const float* g2_bias= (const float*)d_in[25];
  const float* gru_wih= (const float*)d_in[26];
  const float* gru_bih= (const float*)d_in[27];
  const float* gru_whh= (const float*)d_in[28];
  const float* gru_bhh= (const float*)d_in[29];
  const float* dec_w1 = (const float*)d_in[30];
  const float* dec_b1 = (const float*)d_in[31];
  const float* dec_w2 = (const float*)d_in[32];
  const float* dec_b2 = (const float*)d_in[33];

  float* ws = (float*)d_ws;
  float* hA = ws;               // N*64
  float* hB = hA + N_ * 64;     // N*64
  float* xl = hB + N_ * 64;     // N*64
  float* xr = xl + N_ * 64;     // N*64
  int* deg  = (int*)(xr + N_ * 64);  // N
  int* off  = deg + N_;              // N+1
  int* cur  = off + N_ + 1;          // N
  int* bsum = cur + N_;              // 64 (padded -> csr_es stays 8B aligned)
  int2* csr_es = (int2*)(bsum + 64); // E pairs

  float* out0  = (float*)d_out;      // N*7
  float* outnh = out0 + N_ * 7;      // N*64
  float* outa1 = outnh + N_ * 64;    // E*4
  float* outa2 = outa1 + E_ * 4;     // E*4

  const int NB_SCAN = (N_ + 1023) / 1024;  // 49
  const int NB_DENSE = (N_ + 255) / 256;   // 196

  hipMemsetAsync(deg, 0, N_ * sizeof(int), stream);
  k_hist<<<(E_ + 255) / 256, 256, 0, stream>>>(ei, deg);
  k_scan_blk<<<NB_SCAN, 1024, 0, stream>>>(deg, off, bsum);
  k_scan_top<<<1, 64, 0, stream>>>(bsum, NB_SCAN);
  k_scan_add<<<(N_ + 255) / 256, 256, 0, stream>>>(off, bsum, cur);
  k_scatter<<<(E_ + 255) / 256, 256, 0, stream>>>(ei, cur, csr_es);

  k_enc<<<NB_DENSE, 256, 0, stream>>>(x, ntype, sid, temb, semb,
                                      enc_w1, enc_b1, enc_w2, enc_b2, hA);
  // GAT layer 1: hA -> hB (relu)
  k_xlxr<<<NB_DENSE, 256, 0, stream>>>(hA, g1_wl, g1_bl, g1_wr, g1_br, xl, xr);
  k_fused<true><<<2048, 256, 0, stream>>>(off, csr_es, eattr, xl, xr,
                                          g1_we, g1_att, g1_bias, hB, outa1);
  // GAT layer 2: hB -> hA (no relu)
  k_xlxr<<<NB_DENSE, 256, 0, stream>>>(hB, g2_wl, g2_bl, g2_wr, g2_br, xl, xr);
  k_fused<false><<<2048, 256, 0, stream>>>(off, csr_es, eattr, xl, xr,
                                           g2_we, g2_att, g2_bias, hA, outa2);
  // GRU -> outnh (f32 output region doubles as decoder input)
  k_gru<<<NB_DENSE, 256, 0, stream>>>(hA, hs, gru_wih, gru_bih, gru_whh, gru_bhh, outnh);
  // Decoder
  k_dec<<<NB_DENSE, 256, 0, stream>>>(outnh, dec_w1, dec_b1, dec_w2, dec_b2, out0);
}